// Round 8
// baseline (246.016 us; speedup 1.0000x reference)
//
#include <hip/hip_runtime.h>
#include <hip/hip_fp16.h>

typedef _Float16 half_t;
typedef _Float16 half8 __attribute__((ext_vector_type(8)));
typedef float floatx4 __attribute__((ext_vector_type(4)));

static constexpr int BATCH = 2;
static constexpr int NSP = 4096;   // H*W
static constexpr int CH = 512;
static constexpr int NQKV = 3 * CH;  // 1536
static constexpr int KSPLIT = 4;

// ---- ws layout (bytes) ----
static constexpr size_t OFF_STATS = 0;                              // 128 floats
static constexpr size_t OFF_ROWSUM = 512;                           // B*NSP floats (32 KB)
static constexpr size_t OFF_PST = 33280;                            // GN partials
static constexpr size_t OFF_WQKV = 196608;
static constexpr size_t WQKV_BYTES = (size_t)NQKV * CH * 2;         // 1.5 MB
static constexpr size_t OFF_WP = OFF_WQKV + WQKV_BYTES;
static constexpr size_t WP_BYTES = (size_t)CH * CH * 2;             // 0.5 MB
static constexpr size_t OFF_XN = OFF_WP + WP_BYTES;
static constexpr size_t XN_BYTES = (size_t)BATCH * NSP * CH * 2;    // 8 MB
static constexpr size_t OFF_QKV = OFF_XN + XN_BYTES;
static constexpr size_t QKV_BYTES = (size_t)BATCH * NSP * NQKV * 2; // 24 MB
static constexpr size_t OFF_VT = OFF_QKV + QKV_BYTES;
static constexpr size_t OFF_AO = OFF_VT + XN_BYTES;
static constexpr size_t OFF_S = OFF_AO + XN_BYTES;
static constexpr size_t S_BYTES_1 = (size_t)NSP * NSP * 2;          // 32 MB / batch
// PV split-K partials: 8 slabs x 4 MB = 32 MB, overlaying xn+qkv (dead by PV)
static constexpr size_t OFF_PART = OFF_XN;

__device__ __forceinline__ void gld16(void* lds, const void* g) {
  __builtin_amdgcn_global_load_lds(
      (__attribute__((address_space(1))) void*)(g),
      (__attribute__((address_space(3))) void*)(lds),
      16, 0, 0);
}

#define VMCNT(n) asm volatile("s_waitcnt vmcnt(" #n ")" ::: "memory")
#define LGKM0()                                         \
  do {                                                  \
    asm volatile("s_waitcnt lgkmcnt(0)" ::: "memory");  \
    __builtin_amdgcn_sched_barrier(0);                  \
  } while (0)

// ---------------- prep: GN stage-1 stats + weight transposes (merged) ----
__global__ __launch_bounds__(256) void prep(
    const float* __restrict__ x, float* __restrict__ pst,
    const float* __restrict__ w0, const float* __restrict__ w1,
    const float* __restrict__ w2, const float* __restrict__ w3,
    half_t* __restrict__ o0, half_t* __restrict__ o1,
    half_t* __restrict__ o2, half_t* __restrict__ o3) {
  __shared__ float gs[32], gs2[32];
  __shared__ float tw[32][33];
  const int bid = (int)blockIdx.x;
  const int tid = (int)threadIdx.x;
  if (bid < 512) {
    const int b = bid >> 8;
    const int chunk = bid & 255;
    int g = ((tid * 4) & (CH - 1)) >> 4;
    const float* base = x + (long)b * NSP * CH + (long)chunk * 16 * CH + tid * 4;
    float s = 0.f, s2 = 0.f;
#pragma unroll
    for (int it = 0; it < 8; ++it) {
      floatx4 v = *(const floatx4*)(base + (long)it * 1024);
#pragma unroll
      for (int r = 0; r < 4; ++r) { s += v[r]; s2 += v[r] * v[r]; }
    }
    if (tid < 32) { gs[tid] = 0.f; gs2[tid] = 0.f; }
    __syncthreads();
    atomicAdd(&gs[g], s);
    atomicAdd(&gs2[g], s2);
    __syncthreads();
    if (tid < 32) {
      long idx = ((long)(b * 256 + chunk) * 32 + tid) * 2;
      pst[idx] = gs[tid];
      pst[idx + 1] = gs2[tid];
    }
  } else {
    const int t = bid - 512;
    const int wz = t >> 8;
    const int r = t & 255;
    const float* w; half_t* o;
    switch (wz) {
      case 0: w = w0; o = o0; break;
      case 1: w = w1; o = o1; break;
      case 2: w = w2; o = o2; break;
      default: w = w3; o = o3; break;
    }
    int d0 = (r & 15) * 32, c0 = (r >> 4) * 32;
    int tx = tid & 31, ty = tid >> 5;
#pragma unroll
    for (int i = 0; i < 4; ++i)
      tw[ty + i * 8][tx] = w[(long)(c0 + ty + i * 8) * CH + d0 + tx];
    __syncthreads();
#pragma unroll
    for (int i = 0; i < 4; ++i) {
      int d = ty + i * 8;
      o[(long)(d0 + d) * CH + c0 + tx] = (half_t)tw[tx][d];
    }
  }
}

// stage 2: reduce 256 chunks -> mean/rstd per (b,g); also zero rowsum
__global__ __launch_bounds__(256) void gn_finalize(const float* __restrict__ pst,
                                                   float* __restrict__ st,
                                                   float* __restrict__ rowsum) {
  int tid = (int)threadIdx.x;
  int bg = tid & 63;
  int p = tid >> 6;
  int b = bg >> 5, g = bg & 31;
  float s = 0.f, s2 = 0.f;
  for (int j = 0; j < 64; ++j) {
    int chunk = p * 64 + j;
    long idx = ((long)(b * 256 + chunk) * 32 + g) * 2;
    s += pst[idx];
    s2 += pst[idx + 1];
  }
  __shared__ float rs[64][4], rs2[64][4];
  rs[bg][p] = s;
  rs2[bg][p] = s2;
  __syncthreads();
  if (tid < 64) {
    float ts = rs[tid][0] + rs[tid][1] + rs[tid][2] + rs[tid][3];
    float ts2 = rs2[tid][0] + rs2[tid][1] + rs2[tid][2] + rs2[tid][3];
    const float inv = 1.f / 65536.f;
    float mean = ts * inv;
    float var = ts2 * inv - mean * mean;
    st[tid * 2] = mean;
    st[tid * 2 + 1] = rsqrtf(var + 1e-5f);
  }
  floatx4* rz = (floatx4*)rowsum;
#pragma unroll
  for (int j = 0; j < 8; ++j)
    rz[tid + j * 256] = floatx4{0.f, 0.f, 0.f, 0.f};
}

__global__ __launch_bounds__(256) void gn_apply(const float* __restrict__ x,
                                                const float* __restrict__ st,
                                                const float* __restrict__ gamma,
                                                const float* __restrict__ beta,
                                                half_t* __restrict__ xn) {
  long i = ((long)blockIdx.x * 256 + threadIdx.x) * 8;
  int c = (int)(i & (CH - 1));
  int b = (int)(i >> 21);
  int g = c >> 4;
  float mean = st[((b << 5) + g) * 2];
  float rstd = st[((b << 5) + g) * 2 + 1];
  floatx4 a = *(const floatx4*)(x + i);
  floatx4 d = *(const floatx4*)(x + i + 4);
  half8 o;
#pragma unroll
  for (int r = 0; r < 4; ++r) {
    o[r]     = (half_t)((a[r] - mean) * rstd * gamma[c + r] + beta[c + r]);
    o[r + 4] = (half_t)((d[r] - mean) * rstd * gamma[c + r + 4] + beta[c + r + 4]);
  }
  *(half8*)(xn + i) = o;
}

// ---------------- transpose_v (warming removed: r7 null) ----------------
__global__ __launch_bounds__(256) void transpose_v(const half_t* __restrict__ v,
                                                   half_t* __restrict__ vt) {
  __shared__ half_t t[32][33];
  int b = blockIdx.z;
  int d0 = blockIdx.x * 32, n0 = blockIdx.y * 32;
  int tx = threadIdx.x & 31, ty = threadIdx.x >> 5;
  const half_t* vb = v + (long)b * NSP * NQKV;
  half_t* ob = vt + (long)b * NSP * CH;
#pragma unroll
  for (int i = 0; i < 4; ++i)
    t[ty + i * 8][tx] = vb[(long)(n0 + ty + i * 8) * NQKV + d0 + tx];
  __syncthreads();
#pragma unroll
  for (int i = 0; i < 4; ++i) {
    int d = ty + i * 8;
    ob[(long)(d0 + d) * NSP + n0 + tx] = t[tx][d];
  }
}

// ---------------- NT GEMM (QKV + proj) ----------------
template <int BM, int BN, int BK, int EPI, int SWZ, int KSP, typename OutT>
__global__ __launch_bounds__(256) void gemm_nt(
    const half_t* __restrict__ X, const half_t* __restrict__ Y,
    OutT* __restrict__ Co, const float* __restrict__ b0,
    const float* __restrict__ b1, const float* __restrict__ b2,
    const float* __restrict__ resid, float* __restrict__ rowsum,
    int M, int N, int K, int ldx, int ldy, int ldc,
    long xbs, long ybs, long cbs, float scale) {
  constexpr int SM = BM / 32;
  constexpr int SN = BN / 32;
  constexpr int ROWS = BM + BN;
  constexpr int CPR = BK / 8;
  constexpr int RPW = 64 / CPR;
  constexpr int ROUNDS = (ROWS * BK * 2) / 4096;
  constexpr int KSTEPS = BK / 32;
  static_assert(BM % (4 * RPW) == 0, "no As/Bs straddle within a round");
  __shared__ __align__(16) half_t Sh[ROWS * BK];

  const int zb = blockIdx.z / KSP;
  const int ks = blockIdx.z % KSP;
  int bx, by;
  if (SWZ == 1) {
    int lin = (int)(blockIdx.x + gridDim.x * blockIdx.y);
    int wmt = 256 / (int)gridDim.x;
    by = wmt * (lin >> 8) + ((lin & 255) % wmt);
    bx = (lin & 255) / wmt;
  } else if (SWZ == 2) {
    by = blockIdx.x;
    bx = blockIdx.y;
  } else {
    bx = blockIdx.x;
    by = blockIdx.y;
  }

  const half_t* Xb = X + (long)zb * xbs + (long)ks * K;
  const half_t* Yb = Y + (long)zb * ybs + (long)ks * K;
  OutT* Cb = Co + (long)blockIdx.z * cbs;

  const int m0 = by * BM;
  const int n0 = bx * BN;
  const int tid = (int)threadIdx.x;
  const int wave = tid >> 6;
  const int lane = tid & 63;
  const int quad = lane >> 4;
  const int l16 = lane & 15;
  const int wm = wave >> 1;
  const int wn = wave & 1;

  floatx4 acc[SM][SN] = {};

  const int srow = lane / CPR;
  const int schunk = lane % CPR;
  const char* Xc = (const char*)Xb;

  int soff[ROUNDS];
#pragma unroll
  for (int r = 0; r < ROUNDS; ++r) {
    int row = r * (4 * RPW) + wave * RPW + srow;
    int gchunk = schunk ^ (row & (CPR - 1));
    const char* p = (row < BM)
        ? (const char*)(Xb + (long)(m0 + row) * ldx)
        : (const char*)(Yb + (long)(n0 + row - BM) * ldy);
    soff[r] = (int)(p + gchunk * 16 - Xc);
  }

  int offA[SM], offB[SN];
#pragma unroll
  for (int i = 0; i < SM; ++i) {
    int m = wm * (BM / 2) + i * 16 + l16;
    int cc = quad ^ (m & (CPR - 1));
    offA[i] = (m * BK + cc * 8) * 2;
  }
#pragma unroll
  for (int j = 0; j < SN; ++j) {
    int n = wn * (BN / 2) + j * 16 + l16;
    int cc = quad ^ (n & (CPR - 1));
    offB[j] = (BM * BK + n * BK + cc * 8) * 2;
  }

  for (int k0 = 0; k0 < K; k0 += BK) {
#pragma unroll
    for (int r = 0; r < ROUNDS; ++r) {
      gld16((char*)Sh + (r * 4 + wave) * 1024, Xc + (long)soff[r]);
      soff[r] += BK * 2;
    }
    __syncthreads();

#pragma unroll
    for (int kk = 0; kk < KSTEPS; ++kk) {
      const int kx = kk << 6;
      half8 af[SM], bf[SN];
#pragma unroll
      for (int i = 0; i < SM; ++i)
        af[i] = *(const half8*)((const char*)Sh + (offA[i] ^ kx));
#pragma unroll
      for (int j = 0; j < SN; ++j)
        bf[j] = *(const half8*)((const char*)Sh + (offB[j] ^ kx));
#pragma unroll
      for (int i = 0; i < SM; ++i)
#pragma unroll
        for (int j = 0; j < SN; ++j)
          acc[i][j] = __builtin_amdgcn_mfma_f32_16x16x32_f16(af[i], bf[j], acc[i][j], 0, 0, 0);
    }
    __syncthreads();
  }

#pragma unroll
  for (int i = 0; i < SM; ++i) {
    int gmb = m0 + wm * (BM / 2) + i * 16 + quad * 4;
#pragma unroll
    for (int j = 0; j < SN; ++j) {
      int gn = n0 + wn * (BN / 2) + j * 16 + l16;
      float bias = 0.f, sc = 1.f;
      if (EPI == 1) {
        if (gn < CH) { bias = b0[gn]; sc = scale; }
        else if (gn < 2 * CH) { bias = b1[gn - CH]; }
        else { bias = b2[gn - 2 * CH]; }
      } else if (EPI == 2) {
        bias = b0[gn];
      }
#pragma unroll
      for (int r = 0; r < 4; ++r) {
        long idx = (long)(gmb + r) * ldc + gn;
        float v = acc[i][j][r];
        if (EPI == 1) v = (v + bias) * sc;
        if (EPI == 2) v = v + bias + resid[idx];
        Cb[idx] = (OutT)v;
      }
    }
  }
}

// ---------------- 8-phase 256x256 NT GEMM (r2 schedule, frozen) ----------
// SW=1: r6 XCD regions, 1 tile/block.
// SW=2: PV slab swizzle, grid (256,1,1) -- r6.
// SW=3 (TT=2): persistent 2-tile blocks, grid (128,1,BATCH). Each block
//   computes tiles (by, 2*bxp) then (by, 2*bxp+1) -- A panel shared, so
//   tile 2's A staging is L2-warm (within-kernel L2 persistence is the
//   only locality that exists; cross-kernel warming measured null, r7).
//   Tile-2 prologue issued BEFORE tile-1 epilogue: the 14 loads' L3
//   latency hides under the exp/store/atomic epilogue. Unified vmcnt
//   conservatively drains epilogue stores at the tile-2 VMCNT(6) (safe).
//   XCD decode: xcd=x&7, k2=x>>3; by=(xcd&3)*4+(k2&3);
//   bxp=(xcd>>2)*4+(k2>>2). Per XCD: 4 A + 4 B panels x 2 batches ~ 4MB.
template <int EPI, int KSP, int SW, int TT, typename OutT>
__global__ __launch_bounds__(512, 2) void gemm8p(
    const half_t* __restrict__ X, const half_t* __restrict__ Y,
    OutT* __restrict__ Co, float* __restrict__ rowsum,
    int K, int ldx, int ldy, int ldc, long xbs, long ybs, long cbs) {
  __shared__ __align__(16) char smem[131072];
  int by, bx, zb, ks;
  if (SW == 1) {
    const int lin = (int)(blockIdx.x + (blockIdx.y << 4));
    const int xcd = lin & 7;
    const int k2 = lin >> 3;
    by = (xcd & 3) * 4 + (k2 & 3);
    bx = (xcd >> 2) * 8 + (k2 >> 2);
    zb = (int)blockIdx.z / KSP;
    ks = (int)blockIdx.z % KSP;
  } else if (SW == 2) {
    const int xcd = (int)blockIdx.x & 7;
    const int s = (int)blockIdx.x >> 3;
    const int c = xcd * 2 + (s >> 4);
    by = s & 15;
    bx = c & 1;
    ks = (c >> 1) & 3;
    zb = c >> 3;
  } else if (SW == 3) {
    const int xcd = (int)blockIdx.x & 7;
    const int k2 = (int)blockIdx.x >> 3;
    by = (xcd & 3) * 4 + (k2 & 3);
    bx = ((xcd >> 2) * 4 + (k2 >> 2)) * 2;  // first tile of the pair
    zb = (int)blockIdx.z;
    ks = 0;
  } else {
    by = (int)blockIdx.x;
    bx = (int)blockIdx.y;
    zb = (int)blockIdx.z / KSP;
    ks = (int)blockIdx.z % KSP;
  }
  const int m0 = by * 256;
  int n0 = bx * 256;
  const int tid = (int)threadIdx.x;
  const int w = tid >> 6;
  const int l = tid & 63;
  const int quad = l >> 4;
  const int l16 = l & 15;
  const int wm = w >> 2;
  const int wn = w & 3;

  const half_t* Xb = X + (long)zb * xbs + (long)ks * K;
  const half_t* Yb = Y + (long)zb * ybs + (long)ks * K;
  OutT* Cb = Co + ((long)(zb * KSP + ks)) * cbs;
  const char* Xc = (const char*)Xb;

  const int lr = l >> 3;
  const int gsl = (l & 7) ^ (lr & 7);
  int soff[8];
#pragma unroll
  for (int r = 0; r < 8; ++r) {
    const int R = (r * 8 + w) * 8 + lr;
    const char* p = (R < 256)
        ? (const char*)(Xb + (long)(m0 + R) * ldx)
        : (const char*)(Yb + (long)(n0 + R - 256) * ldy);
    soff[r] = (int)(p + gsl * 16 - Xc);
  }

  int offA[8], offB[4];
#pragma unroll
  for (int i = 0; i < 8; ++i) {
    const int m = wm * 128 + i * 16 + l16;
    offA[i] = m * 128 + ((quad ^ (m & 7)) << 4);
  }
#pragma unroll
  for (int j = 0; j < 4; ++j) {
    const int n = wn * 64 + j * 16 + l16;
    offB[j] = 32768 + n * 128 + ((quad ^ (n & 7)) << 4);
  }

  // prologue: tile0 full -> buf0; tile1 {4,5,6,7,0,2} -> buf1
#pragma unroll
  for (int r = 0; r < 8; ++r) {
    gld16(smem + (r * 8 + w) * 1024, Xc + (long)soff[r]);
    soff[r] += 128;
  }
  {
    constexpr int pr[6] = {4, 5, 6, 7, 0, 2};
#pragma unroll
    for (int t = 0; t < 6; ++t) {
      gld16(smem + 65536 + (pr[t] * 8 + w) * 1024, Xc + (long)soff[pr[t]]);
      soff[pr[t]] += 128;
    }
  }

  const int NI = K >> 7;  // 2 K-tiles per iteration
  half8 bf[4][2];

  for (int tt = 0; tt < TT; ++tt) {
    floatx4 acc[8][4] = {};
    VMCNT(6);
    __builtin_amdgcn_s_barrier();

    for (int it = 0; it < NI; ++it) {
      const bool last = (it == NI - 1);
      constexpr int sr0[8] = {1, 4, 6, 0, 1, 4, 6, 0};
      constexpr int sr1[8] = {3, 5, 7, 2, 3, 5, 7, 2};
      constexpr int spar[8] = {1, 0, 0, 0, 0, 1, 1, 1};
      constexpr int hoist[8] = {1, 1, 1, 0, 1, 0, 1, 0};
      half8 af[2][2];
#pragma unroll
      for (int ph = 0; ph < 8; ++ph) {
        const int q = ph & 3;
        const char* bb = smem + (ph >> 2) * 65536;
        if (q == 0) {
#pragma unroll
          for (int j = 0; j < 4; ++j)
#pragma unroll
            for (int kk = 0; kk < 2; ++kk)
              bf[j][kk] = *(const half8*)(bb + (offB[j] ^ (kk << 6)));
#pragma unroll
          for (int i2 = 0; i2 < 2; ++i2)
#pragma unroll
            for (int kk = 0; kk < 2; ++kk)
              af[i2][kk] = *(const half8*)(bb + (offA[i2] ^ (kk << 6)));
        } else if (ph == 6) {
#pragma unroll
          for (int i2 = 0; i2 < 2; ++i2)
#pragma unroll
            for (int kk = 0; kk < 2; ++kk)
              af[i2][kk] = *(const half8*)(bb + (offA[q * 2 + i2] ^ (kk << 6)));
        }
        if (ph == 0 || !last) {
          const int r0 = sr0[ph], r1 = sr1[ph];
          char* db = smem + spar[ph] * 65536;
          gld16(db + (r0 * 8 + w) * 1024, Xc + (long)soff[r0]);
          soff[r0] += 128;
          gld16(db + (r1 * 8 + w) * 1024, Xc + (long)soff[r1]);
          soff[r1] += 128;
        }
        LGKM0();
        __builtin_amdgcn_s_setprio(1);
#pragma unroll
        for (int i2 = 0; i2 < 2; ++i2)
#pragma unroll
          for (int j = 0; j < 4; ++j)
#pragma unroll
            for (int kk = 0; kk < 2; ++kk)
              acc[q * 2 + i2][j] = __builtin_amdgcn_mfma_f32_16x16x32_f16(
                  af[i2][kk], bf[j][kk], acc[q * 2 + i2][j], 0, 0, 0);
        __builtin_amdgcn_s_setprio(0);
        if (ph == 3) {
          if (last) { VMCNT(2); } else { VMCNT(8); }
        } else if (ph == 5) {
          if (last) { VMCNT(0); } else { VMCNT(10); }
        }
        if (hoist[ph]) {
          const int np = ph + 1;
          const int nq = np & 3;
          const char* nb = smem + ((np >> 2) & 1) * 65536;
#pragma unroll
          for (int i2 = 0; i2 < 2; ++i2)
#pragma unroll
            for (int kk = 0; kk < 2; ++kk)
              af[i2][kk] = *(const half8*)(nb + (offA[nq * 2 + i2] ^ (kk << 6)));
          __builtin_amdgcn_sched_barrier(0);
        }
        if (ph == 7) {
          if (!last) { VMCNT(6); }
        }
        __builtin_amdgcn_s_barrier();
      }
    }

    // next tile (TT=2): recompute staging offsets for n0+256, issue the
    // full prologue NOW -- its L3 latency hides under this tile's epilogue.
    if (TT == 2 && tt == 0) {
      const int n1 = n0 + 256;
#pragma unroll
      for (int r = 0; r < 8; ++r) {
        const int R = (r * 8 + w) * 8 + lr;
        const char* p = (R < 256)
            ? (const char*)(Xb + (long)(m0 + R) * ldx)
            : (const char*)(Yb + (long)(n1 + R - 256) * ldy);
        soff[r] = (int)(p + gsl * 16 - Xc);
      }
#pragma unroll
      for (int r = 0; r < 8; ++r) {
        gld16(smem + (r * 8 + w) * 1024, Xc + (long)soff[r]);
        soff[r] += 128;
      }
      constexpr int pr[6] = {4, 5, 6, 7, 0, 2};
#pragma unroll
      for (int t = 0; t < 6; ++t) {
        gld16(smem + 65536 + (pr[t] * 8 + w) * 1024, Xc + (long)soff[pr[t]]);
        soff[pr[t]] += 128;
      }
    }

    // epilogue for tile tt (uses current n0)
#pragma unroll
    for (int i = 0; i < 8; ++i) {
      const int gmb = m0 + wm * 128 + i * 16 + quad * 4;
      float rs[4] = {0.f, 0.f, 0.f, 0.f};
#pragma unroll
      for (int j = 0; j < 4; ++j) {
        const int gn = n0 + wn * 64 + j * 16 + l16;
#pragma unroll
        for (int r = 0; r < 4; ++r) {
          long idx = (long)(gmb + r) * ldc + gn;
          float v = acc[i][j][r];
          if (EPI == 3) { v = __expf(v); rs[r] += v; }
          Cb[idx] = (OutT)v;
        }
      }
      if (EPI == 3) {
#pragma unroll
        for (int r = 0; r < 4; ++r) {
          float v = rs[r];
          v += __shfl_xor(v, 1);
          v += __shfl_xor(v, 2);
          v += __shfl_xor(v, 4);
          v += __shfl_xor(v, 8);
          if (l16 == 0) atomicAdd(&rowsum[(long)zb * NSP + gmb + r], v);
        }
      }
    }
    n0 += 256;
  }
}

// ---------------- PV split-K combine: ao = (sum of slabs) / rowsum --------
__global__ __launch_bounds__(256) void pv_combine(const half_t* __restrict__ part,
                                                  const float* __restrict__ rowsum,
                                                  half_t* __restrict__ ao) {
  const long bNC = (long)NSP * CH;
  long i = ((long)blockIdx.x * 256 + threadIdx.x) * 8;
  int b = (int)(i >> 21);
  long inner = i & ((1L << 21) - 1);
  float inv = 1.f / rowsum[i >> 9];
  float s[8] = {};
#pragma unroll
  for (int ks = 0; ks < KSPLIT; ++ks) {
    half8 h = *(const half8*)(part + ((long)(b * KSPLIT + ks)) * bNC + inner);
#pragma unroll
    for (int r = 0; r < 8; ++r) s[r] += (float)h[r];
  }
  half8 o;
#pragma unroll
  for (int r = 0; r < 8; ++r) o[r] = (half_t)(s[r] * inv);
  *(half8*)(ao + i) = o;
}

extern "C" void kernel_launch(void* const* d_in, const int* in_sizes, int n_in,
                              void* d_out, int out_size, void* d_ws, size_t ws_size,
                              hipStream_t stream) {
  const float* x = (const float*)d_in[0];
  const float* gamma = (const float*)d_in[1];
  const float* beta = (const float*)d_in[2];
  const float* wq = (const float*)d_in[3];
  const float* bq = (const float*)d_in[4];
  const float* wk = (const float*)d_in[5];
  const float* bk = (const float*)d_in[6];
  const float* wv = (const float*)d_in[7];
  const float* bv = (const float*)d_in[8];
  const float* wp = (const float*)d_in[9];
  const float* bp = (const float*)d_in[10];
  float* out = (float*)d_out;
  char* ws = (char*)d_ws;

  float* st = (float*)(ws + OFF_STATS);
  float* rsum = (float*)(ws + OFF_ROWSUM);
  float* pst = (float*)(ws + OFF_PST);
  half_t* wqkvT = (half_t*)(ws + OFF_WQKV);
  half_t* wpT = (half_t*)(ws + OFF_WP);
  half_t* xn = (half_t*)(ws + OFF_XN);
  half_t* qkv = (half_t*)(ws + OFF_QKV);
  half_t* vt = (half_t*)(ws + OFF_VT);
  half_t* ao = (half_t*)(ws + OFF_AO);
  half_t* S = (half_t*)(ws + OFF_S);
  half_t* part = (half_t*)(ws + OFF_PART);

  half_t* q = qkv;            // ld NQKV
  half_t* k = qkv + CH;       // ld NQKV
  half_t* v = qkv + 2 * CH;   // ld NQKV

  const float scale = 0.044194173824159216f;  // 1/sqrt(512)
  const long bQKV = (long)NSP * NQKV;
  const long bNC = (long)NSP * CH;
  const long bNN = (long)NSP * NSP;

  // merged GN stats + weight transposes
  prep<<<1536, 256, 0, stream>>>(x, pst, wq, wk, wv, wp,
      wqkvT, wqkvT + (size_t)CH * CH, wqkvT + 2 * (size_t)CH * CH, wpT);
  gn_finalize<<<1, 256, 0, stream>>>(pst, st, rsum);
  gn_apply<<<2048, 256, 0, stream>>>(x, st, gamma, beta, xn);

  // fused qkv = xn @ [wq|wk|wv]^T + bias (q scaled)
  gemm_nt<128, 128, 64, 1, 2, 1, half_t><<<dim3(BATCH * NSP / 128, NQKV / 128, 1), 256, 0, stream>>>(
      xn, wqkvT, qkv, bq, bk, bv, nullptr, nullptr, BATCH * NSP, NQKV, CH,
      CH, CH, NQKV, 0, 0, 0, scale);
  transpose_v<<<dim3(16, 128, BATCH), 256, 0, stream>>>(v, vt);

  bool full = ws_size >= OFF_S + 2 * S_BYTES_1;
  if (full) {
    // scores: 8-phase 256x256, persistent 2-tile blocks (A-panel reuse)
    gemm8p<3, 1, 3, 2, half_t><<<dim3(128, 1, BATCH), 512, 0, stream>>>(
        q, k, S, rsum, CH, NQKV, NQKV, NSP, bQKV, bQKV, bNN);
    // PV split-K: 8-phase 256x256, slab swizzle (vt L2-resident per XCD)
    gemm8p<0, KSPLIT, 2, 1, half_t><<<dim3(256, 1, 1), 512, 0, stream>>>(
        S, vt, part, nullptr, NSP / KSPLIT, NSP, NSP, CH, bNN, bNC, bNC);
    pv_combine<<<2048, 256, 0, stream>>>(part, rsum, ao);
  } else {
    for (int bb = 0; bb < BATCH; ++bb) {
      gemm8p<3, 1, 1, 1, half_t><<<dim3(16, 16, 1), 512, 0, stream>>>(
          q + bb * bQKV, k + bb * bQKV, S, rsum + bb * NSP, CH,
          NQKV, NQKV, NSP, 0, 0, 0);
      gemm8p<0, KSPLIT, 0, 1, half_t><<<dim3(NSP / 256, CH / 256, KSPLIT), 512, 0, stream>>>(
          S, vt + bb * bNC, part + (long)bb * KSPLIT * bNC, nullptr,
          NSP / KSPLIT, NSP, NSP, CH, 0, 0, bNC);
    }
    pv_combine<<<2048, 256, 0, stream>>>(part, rsum, ao);
  }
  // out = ao @ wp^T + bp + x
  gemm_nt<64, 64, 128, 2, 2, 1, float><<<dim3(BATCH * NSP / 64, CH / 64, 1), 256, 0, stream>>>(
      ao, wpT, out, bp, nullptr, nullptr, x, nullptr, BATCH * NSP, CH, CH,
      CH, CH, CH, 0, 0, 0, 1.f);
}

// Round 9
// 229.859 us; speedup vs baseline: 1.0703x; 1.0703x over previous
//
#include <hip/hip_runtime.h>
#include <hip/hip_fp16.h>

typedef _Float16 half_t;
typedef _Float16 half8 __attribute__((ext_vector_type(8)));
typedef float floatx4 __attribute__((ext_vector_type(4)));

static constexpr int BATCH = 2;
static constexpr int NSP = 4096;   // H*W
static constexpr int CH = 512;
static constexpr int NQKV = 3 * CH;  // 1536
static constexpr int KSPLIT = 4;

// ---- ws layout (bytes) ----
static constexpr size_t OFF_STATS = 0;                              // 128 floats
static constexpr size_t OFF_ROWSUM = 512;                           // B*NSP floats (32 KB)
static constexpr size_t OFF_PST = 33280;                            // GN partials
static constexpr size_t OFF_WQKV = 196608;
static constexpr size_t WQKV_BYTES = (size_t)NQKV * CH * 2;         // 1.5 MB
static constexpr size_t OFF_WP = OFF_WQKV + WQKV_BYTES;
static constexpr size_t WP_BYTES = (size_t)CH * CH * 2;             // 0.5 MB
static constexpr size_t OFF_XN = OFF_WP + WP_BYTES;
static constexpr size_t XN_BYTES = (size_t)BATCH * NSP * CH * 2;    // 8 MB
static constexpr size_t OFF_QKV = OFF_XN + XN_BYTES;
static constexpr size_t QKV_BYTES = (size_t)BATCH * NSP * NQKV * 2; // 24 MB
static constexpr size_t OFF_VT = OFF_QKV + QKV_BYTES;
static constexpr size_t OFF_AO = OFF_VT + XN_BYTES;
static constexpr size_t OFF_S = OFF_AO + XN_BYTES;
static constexpr size_t S_BYTES_1 = (size_t)NSP * NSP * 2;          // 32 MB / batch
// PV split-K partials: 8 slabs x 4 MB = 32 MB, overlaying xn+qkv (dead by PV)
static constexpr size_t OFF_PART = OFF_XN;

__device__ __forceinline__ void gld16(void* lds, const void* g) {
  __builtin_amdgcn_global_load_lds(
      (__attribute__((address_space(1))) void*)(g),
      (__attribute__((address_space(3))) void*)(lds),
      16, 0, 0);
}

#define VMCNT(n) asm volatile("s_waitcnt vmcnt(" #n ")" ::: "memory")
#define LGKM0()                                         \
  do {                                                  \
    asm volatile("s_waitcnt lgkmcnt(0)" ::: "memory");  \
    __builtin_amdgcn_sched_barrier(0);                  \
  } while (0)

// ---------------- prep: GN stage-1 stats + weight transposes (merged) ----
__global__ __launch_bounds__(256) void prep(
    const float* __restrict__ x, float* __restrict__ pst,
    const float* __restrict__ w0, const float* __restrict__ w1,
    const float* __restrict__ w2, const float* __restrict__ w3,
    half_t* __restrict__ o0, half_t* __restrict__ o1,
    half_t* __restrict__ o2, half_t* __restrict__ o3) {
  __shared__ float gs[32], gs2[32];
  __shared__ float tw[32][33];
  const int bid = (int)blockIdx.x;
  const int tid = (int)threadIdx.x;
  if (bid < 512) {
    const int b = bid >> 8;
    const int chunk = bid & 255;
    int g = ((tid * 4) & (CH - 1)) >> 4;
    const float* base = x + (long)b * NSP * CH + (long)chunk * 16 * CH + tid * 4;
    float s = 0.f, s2 = 0.f;
#pragma unroll
    for (int it = 0; it < 8; ++it) {
      floatx4 v = *(const floatx4*)(base + (long)it * 1024);
#pragma unroll
      for (int r = 0; r < 4; ++r) { s += v[r]; s2 += v[r] * v[r]; }
    }
    if (tid < 32) { gs[tid] = 0.f; gs2[tid] = 0.f; }
    __syncthreads();
    atomicAdd(&gs[g], s);
    atomicAdd(&gs2[g], s2);
    __syncthreads();
    if (tid < 32) {
      long idx = ((long)(b * 256 + chunk) * 32 + tid) * 2;
      pst[idx] = gs[tid];
      pst[idx + 1] = gs2[tid];
    }
  } else {
    const int t = bid - 512;
    const int wz = t >> 8;
    const int r = t & 255;
    const float* w; half_t* o;
    switch (wz) {
      case 0: w = w0; o = o0; break;
      case 1: w = w1; o = o1; break;
      case 2: w = w2; o = o2; break;
      default: w = w3; o = o3; break;
    }
    int d0 = (r & 15) * 32, c0 = (r >> 4) * 32;
    int tx = tid & 31, ty = tid >> 5;
#pragma unroll
    for (int i = 0; i < 4; ++i)
      tw[ty + i * 8][tx] = w[(long)(c0 + ty + i * 8) * CH + d0 + tx];
    __syncthreads();
#pragma unroll
    for (int i = 0; i < 4; ++i) {
      int d = ty + i * 8;
      o[(long)(d0 + d) * CH + c0 + tx] = (half_t)tw[tx][d];
    }
  }
}

// stage 2: reduce 256 chunks -> mean/rstd per (b,g); also zero rowsum
__global__ __launch_bounds__(256) void gn_finalize(const float* __restrict__ pst,
                                                   float* __restrict__ st,
                                                   float* __restrict__ rowsum) {
  int tid = (int)threadIdx.x;
  int bg = tid & 63;
  int p = tid >> 6;
  int b = bg >> 5, g = bg & 31;
  float s = 0.f, s2 = 0.f;
  for (int j = 0; j < 64; ++j) {
    int chunk = p * 64 + j;
    long idx = ((long)(b * 256 + chunk) * 32 + g) * 2;
    s += pst[idx];
    s2 += pst[idx + 1];
  }
  __shared__ float rs[64][4], rs2[64][4];
  rs[bg][p] = s;
  rs2[bg][p] = s2;
  __syncthreads();
  if (tid < 64) {
    float ts = rs[tid][0] + rs[tid][1] + rs[tid][2] + rs[tid][3];
    float ts2 = rs2[tid][0] + rs2[tid][1] + rs2[tid][2] + rs2[tid][3];
    const float inv = 1.f / 65536.f;
    float mean = ts * inv;
    float var = ts2 * inv - mean * mean;
    st[tid * 2] = mean;
    st[tid * 2 + 1] = rsqrtf(var + 1e-5f);
  }
  floatx4* rz = (floatx4*)rowsum;
#pragma unroll
  for (int j = 0; j < 8; ++j)
    rz[tid + j * 256] = floatx4{0.f, 0.f, 0.f, 0.f};
}

__global__ __launch_bounds__(256) void gn_apply(const float* __restrict__ x,
                                                const float* __restrict__ st,
                                                const float* __restrict__ gamma,
                                                const float* __restrict__ beta,
                                                half_t* __restrict__ xn) {
  long i = ((long)blockIdx.x * 256 + threadIdx.x) * 8;
  int c = (int)(i & (CH - 1));
  int b = (int)(i >> 21);
  int g = c >> 4;
  float mean = st[((b << 5) + g) * 2];
  float rstd = st[((b << 5) + g) * 2 + 1];
  floatx4 a = *(const floatx4*)(x + i);
  floatx4 d = *(const floatx4*)(x + i + 4);
  half8 o;
#pragma unroll
  for (int r = 0; r < 4; ++r) {
    o[r]     = (half_t)((a[r] - mean) * rstd * gamma[c + r] + beta[c + r]);
    o[r + 4] = (half_t)((d[r] - mean) * rstd * gamma[c + r + 4] + beta[c + r + 4]);
  }
  *(half8*)(xn + i) = o;
}

// ---------------- transpose_v ----------------
__global__ __launch_bounds__(256) void transpose_v(const half_t* __restrict__ v,
                                                   half_t* __restrict__ vt) {
  __shared__ half_t t[32][33];
  int b = blockIdx.z;
  int d0 = blockIdx.x * 32, n0 = blockIdx.y * 32;
  int tx = threadIdx.x & 31, ty = threadIdx.x >> 5;
  const half_t* vb = v + (long)b * NSP * NQKV;
  half_t* ob = vt + (long)b * NSP * CH;
#pragma unroll
  for (int i = 0; i < 4; ++i)
    t[ty + i * 8][tx] = vb[(long)(n0 + ty + i * 8) * NQKV + d0 + tx];
  __syncthreads();
#pragma unroll
  for (int i = 0; i < 4; ++i) {
    int d = ty + i * 8;
    ob[(long)(d0 + d) * NSP + n0 + tx] = t[tx][d];
  }
}

// ---------------- NT GEMM (QKV + proj) ----------------
// EPI=1: fused QKV bias epilogue. EPI=2: proj (bias+resid) from ao.
// EPI=4: proj with FUSED split-K combine: X = part (KSPLIT slabs of
//   unnormalized PV partials); X rows are reg-staged as
//   (sum of slabs) * (1/rowsum[m]) and ds_written into the SAME LDS
//   layout the gld16 path produces (same pre-swizzled chunk pattern).
//   Y (wpT) staging stays gld16. Epilogue = EPI2 (bias + resid).
template <int BM, int BN, int BK, int EPI, int SWZ, int KSP, typename OutT>
__global__ __launch_bounds__(256) void gemm_nt(
    const half_t* __restrict__ X, const half_t* __restrict__ Y,
    OutT* __restrict__ Co, const float* __restrict__ b0,
    const float* __restrict__ b1, const float* __restrict__ b2,
    const float* __restrict__ resid, float* __restrict__ rowsum,
    int M, int N, int K, int ldx, int ldy, int ldc,
    long xbs, long ybs, long cbs, float scale) {
  constexpr int SM = BM / 32;
  constexpr int SN = BN / 32;
  constexpr int ROWS = BM + BN;
  constexpr int CPR = BK / 8;
  constexpr int RPW = 64 / CPR;
  constexpr int ROUNDS = (ROWS * BK * 2) / 4096;
  constexpr int KSTEPS = BK / 32;
  static_assert(BM % (4 * RPW) == 0, "no As/Bs straddle within a round");
  __shared__ __align__(16) half_t Sh[ROWS * BK];

  const int zb = blockIdx.z / KSP;
  const int ks = blockIdx.z % KSP;
  int bx, by;
  if (SWZ == 1) {
    int lin = (int)(blockIdx.x + gridDim.x * blockIdx.y);
    int wmt = 256 / (int)gridDim.x;
    by = wmt * (lin >> 8) + ((lin & 255) % wmt);
    bx = (lin & 255) / wmt;
  } else if (SWZ == 2) {
    by = blockIdx.x;
    bx = blockIdx.y;
  } else {
    bx = blockIdx.x;
    by = blockIdx.y;
  }

  const half_t* Xb = X + (long)zb * xbs + (long)ks * K;
  const half_t* Yb = Y + (long)zb * ybs + (long)ks * K;
  OutT* Cb = Co + (long)blockIdx.z * cbs;

  const int m0 = by * BM;
  const int n0 = bx * BN;
  const int tid = (int)threadIdx.x;
  const int wave = tid >> 6;
  const int lane = tid & 63;
  const int quad = lane >> 4;
  const int l16 = lane & 15;
  const int wm = wave >> 1;
  const int wn = wave & 1;

  floatx4 acc[SM][SN] = {};

  const int srow = lane / CPR;
  const int schunk = lane % CPR;
  const char* Xc = (const char*)Xb;

  int soff[ROUNDS];
  int xoff[ROUNDS];
  float xinv[ROUNDS];
#pragma unroll
  for (int r = 0; r < ROUNDS; ++r) {
    int row = r * (4 * RPW) + wave * RPW + srow;
    int gchunk = schunk ^ (row & (CPR - 1));
    const char* p = (row < BM)
        ? (const char*)(Xb + (long)(m0 + row) * ldx)
        : (const char*)(Yb + (long)(n0 + row - BM) * ldy);
    soff[r] = (int)(p + gchunk * 16 - Xc);
    if (EPI == 4) {
      if (row < BM) {
        int m = m0 + row;                 // global output row (0..B*NSP)
        int zbm = m >> 12;                // batch
        int inner = m & (NSP - 1);
        xoff[r] = zbm * (KSPLIT * NSP * CH) + inner * CH + gchunk * 8;
        xinv[r] = 1.f / rowsum[m];
      } else {
        xoff[r] = 0;
        xinv[r] = 0.f;
      }
    }
  }

  int offA[SM], offB[SN];
#pragma unroll
  for (int i = 0; i < SM; ++i) {
    int m = wm * (BM / 2) + i * 16 + l16;
    int cc = quad ^ (m & (CPR - 1));
    offA[i] = (m * BK + cc * 8) * 2;
  }
#pragma unroll
  for (int j = 0; j < SN; ++j) {
    int n = wn * (BN / 2) + j * 16 + l16;
    int cc = quad ^ (n & (CPR - 1));
    offB[j] = (BM * BK + n * BK + cc * 8) * 2;
  }

  for (int k0 = 0; k0 < K; k0 += BK) {
    // async Y (and X when not fused) staging
#pragma unroll
    for (int r = 0; r < ROUNDS; ++r) {
      int row = r * (4 * RPW) + wave * RPW + srow;
      if (EPI == 4 && row < BM) continue;
      gld16((char*)Sh + (r * 4 + wave) * 1024, Xc + (long)soff[r]);
      soff[r] += BK * 2;
    }
    if (EPI == 4) {
      // reg-staged X: combine KSPLIT slabs, normalize, ds_write
#pragma unroll
      for (int r = 0; r < ROUNDS; ++r) {
        int row = r * (4 * RPW) + wave * RPW + srow;
        if (row >= BM) continue;
        const half_t* pp = X + xoff[r];
        float s[8] = {};
#pragma unroll
        for (int s4 = 0; s4 < KSPLIT; ++s4) {
          half8 h = *(const half8*)(pp + (long)s4 * (NSP * (long)CH));
#pragma unroll
          for (int e = 0; e < 8; ++e) s[e] += (float)h[e];
        }
        half8 o;
#pragma unroll
        for (int e = 0; e < 8; ++e) o[e] = (half_t)(s[e] * xinv[r]);
        *(half8*)((char*)Sh + (r * 4 + wave) * 1024 + lane * 16) = o;
        xoff[r] += BK;
      }
    }
    __syncthreads();

#pragma unroll
    for (int kk = 0; kk < KSTEPS; ++kk) {
      const int kx = kk << 6;
      half8 af[SM], bf[SN];
#pragma unroll
      for (int i = 0; i < SM; ++i)
        af[i] = *(const half8*)((const char*)Sh + (offA[i] ^ kx));
#pragma unroll
      for (int j = 0; j < SN; ++j)
        bf[j] = *(const half8*)((const char*)Sh + (offB[j] ^ kx));
#pragma unroll
      for (int i = 0; i < SM; ++i)
#pragma unroll
        for (int j = 0; j < SN; ++j)
          acc[i][j] = __builtin_amdgcn_mfma_f32_16x16x32_f16(af[i], bf[j], acc[i][j], 0, 0, 0);
    }
    __syncthreads();
  }

#pragma unroll
  for (int i = 0; i < SM; ++i) {
    int gmb = m0 + wm * (BM / 2) + i * 16 + quad * 4;
#pragma unroll
    for (int j = 0; j < SN; ++j) {
      int gn = n0 + wn * (BN / 2) + j * 16 + l16;
      float bias = 0.f, sc = 1.f;
      if (EPI == 1) {
        if (gn < CH) { bias = b0[gn]; sc = scale; }
        else if (gn < 2 * CH) { bias = b1[gn - CH]; }
        else { bias = b2[gn - 2 * CH]; }
      } else if (EPI == 2 || EPI == 4) {
        bias = b0[gn];
      }
#pragma unroll
      for (int r = 0; r < 4; ++r) {
        long idx = (long)(gmb + r) * ldc + gn;
        float v = acc[i][j][r];
        if (EPI == 1) v = (v + bias) * sc;
        if (EPI == 2 || EPI == 4) v = v + bias + resid[idx];
        Cb[idx] = (OutT)v;
      }
    }
  }
}

// ---------------- 8-phase 256x256 NT GEMM (r2 schedule, frozen) ----------
// SW=1: r6 XCD regions (4m x 8n per XCD, 3MB L2 set) -- the locality
//       optimum (r8's 2-tile persistence blew the per-XCD set to 9MB).
// SW=2: PV slab swizzle, grid (256,1,1).
// SW=0: plain (fallback). TT kept but launched TT=1 everywhere.
template <int EPI, int KSP, int SW, int TT, typename OutT>
__global__ __launch_bounds__(512, 2) void gemm8p(
    const half_t* __restrict__ X, const half_t* __restrict__ Y,
    OutT* __restrict__ Co, float* __restrict__ rowsum,
    int K, int ldx, int ldy, int ldc, long xbs, long ybs, long cbs) {
  __shared__ __align__(16) char smem[131072];
  int by, bx, zb, ks;
  if (SW == 1) {
    const int lin = (int)(blockIdx.x + (blockIdx.y << 4));
    const int xcd = lin & 7;
    const int k2 = lin >> 3;
    by = (xcd & 3) * 4 + (k2 & 3);
    bx = (xcd >> 2) * 8 + (k2 >> 2);
    zb = (int)blockIdx.z / KSP;
    ks = (int)blockIdx.z % KSP;
  } else if (SW == 2) {
    const int xcd = (int)blockIdx.x & 7;
    const int s = (int)blockIdx.x >> 3;
    const int c = xcd * 2 + (s >> 4);
    by = s & 15;
    bx = c & 1;
    ks = (c >> 1) & 3;
    zb = c >> 3;
  } else if (SW == 3) {
    const int xcd = (int)blockIdx.x & 7;
    const int k2 = (int)blockIdx.x >> 3;
    by = (xcd & 3) * 4 + (k2 & 3);
    bx = ((xcd >> 2) * 4 + (k2 >> 2)) * 2;
    zb = (int)blockIdx.z;
    ks = 0;
  } else {
    by = (int)blockIdx.x;
    bx = (int)blockIdx.y;
    zb = (int)blockIdx.z / KSP;
    ks = (int)blockIdx.z % KSP;
  }
  const int m0 = by * 256;
  int n0 = bx * 256;
  const int tid = (int)threadIdx.x;
  const int w = tid >> 6;
  const int l = tid & 63;
  const int quad = l >> 4;
  const int l16 = l & 15;
  const int wm = w >> 2;
  const int wn = w & 3;

  const half_t* Xb = X + (long)zb * xbs + (long)ks * K;
  const half_t* Yb = Y + (long)zb * ybs + (long)ks * K;
  OutT* Cb = Co + ((long)(zb * KSP + ks)) * cbs;
  const char* Xc = (const char*)Xb;

  const int lr = l >> 3;
  const int gsl = (l & 7) ^ (lr & 7);
  int soff[8];
#pragma unroll
  for (int r = 0; r < 8; ++r) {
    const int R = (r * 8 + w) * 8 + lr;
    const char* p = (R < 256)
        ? (const char*)(Xb + (long)(m0 + R) * ldx)
        : (const char*)(Yb + (long)(n0 + R - 256) * ldy);
    soff[r] = (int)(p + gsl * 16 - Xc);
  }

  int offA[8], offB[4];
#pragma unroll
  for (int i = 0; i < 8; ++i) {
    const int m = wm * 128 + i * 16 + l16;
    offA[i] = m * 128 + ((quad ^ (m & 7)) << 4);
  }
#pragma unroll
  for (int j = 0; j < 4; ++j) {
    const int n = wn * 64 + j * 16 + l16;
    offB[j] = 32768 + n * 128 + ((quad ^ (n & 7)) << 4);
  }

  // prologue: tile0 full -> buf0; tile1 {4,5,6,7,0,2} -> buf1
#pragma unroll
  for (int r = 0; r < 8; ++r) {
    gld16(smem + (r * 8 + w) * 1024, Xc + (long)soff[r]);
    soff[r] += 128;
  }
  {
    constexpr int pr[6] = {4, 5, 6, 7, 0, 2};
#pragma unroll
    for (int t = 0; t < 6; ++t) {
      gld16(smem + 65536 + (pr[t] * 8 + w) * 1024, Xc + (long)soff[pr[t]]);
      soff[pr[t]] += 128;
    }
  }

  const int NI = K >> 7;  // 2 K-tiles per iteration
  half8 bf[4][2];

  for (int tt = 0; tt < TT; ++tt) {
    floatx4 acc[8][4] = {};
    VMCNT(6);
    __builtin_amdgcn_s_barrier();

    for (int it = 0; it < NI; ++it) {
      const bool last = (it == NI - 1);
      constexpr int sr0[8] = {1, 4, 6, 0, 1, 4, 6, 0};
      constexpr int sr1[8] = {3, 5, 7, 2, 3, 5, 7, 2};
      constexpr int spar[8] = {1, 0, 0, 0, 0, 1, 1, 1};
      constexpr int hoist[8] = {1, 1, 1, 0, 1, 0, 1, 0};
      half8 af[2][2];
#pragma unroll
      for (int ph = 0; ph < 8; ++ph) {
        const int q = ph & 3;
        const char* bb = smem + (ph >> 2) * 65536;
        if (q == 0) {
#pragma unroll
          for (int j = 0; j < 4; ++j)
#pragma unroll
            for (int kk = 0; kk < 2; ++kk)
              bf[j][kk] = *(const half8*)(bb + (offB[j] ^ (kk << 6)));
#pragma unroll
          for (int i2 = 0; i2 < 2; ++i2)
#pragma unroll
            for (int kk = 0; kk < 2; ++kk)
              af[i2][kk] = *(const half8*)(bb + (offA[i2] ^ (kk << 6)));
        } else if (ph == 6) {
#pragma unroll
          for (int i2 = 0; i2 < 2; ++i2)
#pragma unroll
            for (int kk = 0; kk < 2; ++kk)
              af[i2][kk] = *(const half8*)(bb + (offA[q * 2 + i2] ^ (kk << 6)));
        }
        if (ph == 0 || !last) {
          const int r0 = sr0[ph], r1 = sr1[ph];
          char* db = smem + spar[ph] * 65536;
          gld16(db + (r0 * 8 + w) * 1024, Xc + (long)soff[r0]);
          soff[r0] += 128;
          gld16(db + (r1 * 8 + w) * 1024, Xc + (long)soff[r1]);
          soff[r1] += 128;
        }
        LGKM0();
        __builtin_amdgcn_s_setprio(1);
#pragma unroll
        for (int i2 = 0; i2 < 2; ++i2)
#pragma unroll
          for (int j = 0; j < 4; ++j)
#pragma unroll
            for (int kk = 0; kk < 2; ++kk)
              acc[q * 2 + i2][j] = __builtin_amdgcn_mfma_f32_16x16x32_f16(
                  af[i2][kk], bf[j][kk], acc[q * 2 + i2][j], 0, 0, 0);
        __builtin_amdgcn_s_setprio(0);
        if (ph == 3) {
          if (last) { VMCNT(2); } else { VMCNT(8); }
        } else if (ph == 5) {
          if (last) { VMCNT(0); } else { VMCNT(10); }
        }
        if (hoist[ph]) {
          const int np = ph + 1;
          const int nq = np & 3;
          const char* nb = smem + ((np >> 2) & 1) * 65536;
#pragma unroll
          for (int i2 = 0; i2 < 2; ++i2)
#pragma unroll
            for (int kk = 0; kk < 2; ++kk)
              af[i2][kk] = *(const half8*)(nb + (offA[nq * 2 + i2] ^ (kk << 6)));
          __builtin_amdgcn_sched_barrier(0);
        }
        if (ph == 7) {
          if (!last) { VMCNT(6); }
        }
        __builtin_amdgcn_s_barrier();
      }
    }

    if (TT == 2 && tt == 0) {
      const int n1 = n0 + 256;
#pragma unroll
      for (int r = 0; r < 8; ++r) {
        const int R = (r * 8 + w) * 8 + lr;
        const char* p = (R < 256)
            ? (const char*)(Xb + (long)(m0 + R) * ldx)
            : (const char*)(Yb + (long)(n1 + R - 256) * ldy);
        soff[r] = (int)(p + gsl * 16 - Xc);
      }
#pragma unroll
      for (int r = 0; r < 8; ++r) {
        gld16(smem + (r * 8 + w) * 1024, Xc + (long)soff[r]);
        soff[r] += 128;
      }
      constexpr int pr[6] = {4, 5, 6, 7, 0, 2};
#pragma unroll
      for (int t = 0; t < 6; ++t) {
        gld16(smem + 65536 + (pr[t] * 8 + w) * 1024, Xc + (long)soff[pr[t]]);
        soff[pr[t]] += 128;
      }
    }

    // epilogue for tile tt
#pragma unroll
    for (int i = 0; i < 8; ++i) {
      const int gmb = m0 + wm * 128 + i * 16 + quad * 4;
      float rs[4] = {0.f, 0.f, 0.f, 0.f};
#pragma unroll
      for (int j = 0; j < 4; ++j) {
        const int gn = n0 + wn * 64 + j * 16 + l16;
#pragma unroll
        for (int r = 0; r < 4; ++r) {
          long idx = (long)(gmb + r) * ldc + gn;
          float v = acc[i][j][r];
          if (EPI == 3) { v = __expf(v); rs[r] += v; }
          Cb[idx] = (OutT)v;
        }
      }
      if (EPI == 3) {
#pragma unroll
        for (int r = 0; r < 4; ++r) {
          float v = rs[r];
          v += __shfl_xor(v, 1);
          v += __shfl_xor(v, 2);
          v += __shfl_xor(v, 4);
          v += __shfl_xor(v, 8);
          if (l16 == 0) atomicAdd(&rowsum[(long)zb * NSP + gmb + r], v);
        }
      }
    }
    n0 += 256;
  }
}

// ---------------- PV split-K combine (fallback path only) --------
__global__ __launch_bounds__(256) void pv_combine(const half_t* __restrict__ part,
                                                  const float* __restrict__ rowsum,
                                                  half_t* __restrict__ ao) {
  const long bNC = (long)NSP * CH;
  long i = ((long)blockIdx.x * 256 + threadIdx.x) * 8;
  int b = (int)(i >> 21);
  long inner = i & ((1L << 21) - 1);
  float inv = 1.f / rowsum[i >> 9];
  float s[8] = {};
#pragma unroll
  for (int ks = 0; ks < KSPLIT; ++ks) {
    half8 h = *(const half8*)(part + ((long)(b * KSPLIT + ks)) * bNC + inner);
#pragma unroll
    for (int r = 0; r < 8; ++r) s[r] += (float)h[r];
  }
  half8 o;
#pragma unroll
  for (int r = 0; r < 8; ++r) o[r] = (half_t)(s[r] * inv);
  *(half8*)(ao + i) = o;
}

extern "C" void kernel_launch(void* const* d_in, const int* in_sizes, int n_in,
                              void* d_out, int out_size, void* d_ws, size_t ws_size,
                              hipStream_t stream) {
  const float* x = (const float*)d_in[0];
  const float* gamma = (const float*)d_in[1];
  const float* beta = (const float*)d_in[2];
  const float* wq = (const float*)d_in[3];
  const float* bq = (const float*)d_in[4];
  const float* wk = (const float*)d_in[5];
  const float* bk = (const float*)d_in[6];
  const float* wv = (const float*)d_in[7];
  const float* bv = (const float*)d_in[8];
  const float* wp = (const float*)d_in[9];
  const float* bp = (const float*)d_in[10];
  float* out = (float*)d_out;
  char* ws = (char*)d_ws;

  float* st = (float*)(ws + OFF_STATS);
  float* rsum = (float*)(ws + OFF_ROWSUM);
  float* pst = (float*)(ws + OFF_PST);
  half_t* wqkvT = (half_t*)(ws + OFF_WQKV);
  half_t* wpT = (half_t*)(ws + OFF_WP);
  half_t* xn = (half_t*)(ws + OFF_XN);
  half_t* qkv = (half_t*)(ws + OFF_QKV);
  half_t* vt = (half_t*)(ws + OFF_VT);
  half_t* ao = (half_t*)(ws + OFF_AO);
  half_t* S = (half_t*)(ws + OFF_S);
  half_t* part = (half_t*)(ws + OFF_PART);

  half_t* q = qkv;            // ld NQKV
  half_t* k = qkv + CH;       // ld NQKV
  half_t* v = qkv + 2 * CH;   // ld NQKV

  const float scale = 0.044194173824159216f;  // 1/sqrt(512)
  const long bQKV = (long)NSP * NQKV;
  const long bNC = (long)NSP * CH;
  const long bNN = (long)NSP * NSP;

  // merged GN stats + weight transposes
  prep<<<1536, 256, 0, stream>>>(x, pst, wq, wk, wv, wp,
      wqkvT, wqkvT + (size_t)CH * CH, wqkvT + 2 * (size_t)CH * CH, wpT);
  gn_finalize<<<1, 256, 0, stream>>>(pst, st, rsum);
  gn_apply<<<2048, 256, 0, stream>>>(x, st, gamma, beta, xn);

  // fused qkv = xn @ [wq|wk|wv]^T + bias (q scaled)
  gemm_nt<128, 128, 64, 1, 2, 1, half_t><<<dim3(BATCH * NSP / 128, NQKV / 128, 1), 256, 0, stream>>>(
      xn, wqkvT, qkv, bq, bk, bv, nullptr, nullptr, BATCH * NSP, NQKV, CH,
      CH, CH, NQKV, 0, 0, 0, scale);
  transpose_v<<<dim3(16, 128, BATCH), 256, 0, stream>>>(v, vt);

  bool full = ws_size >= OFF_S + 2 * S_BYTES_1;
  if (full) {
    // scores -> exp(s) + row sums: 8-phase 256x256, r6 XCD-region swizzle
    gemm8p<3, 1, 1, 1, half_t><<<dim3(16, 16, BATCH), 512, 0, stream>>>(
        q, k, S, rsum, CH, NQKV, NQKV, NSP, bQKV, bQKV, bNN);
    // PV split-K: 8-phase 256x256, slab swizzle (vt L2-resident per XCD)
    gemm8p<0, KSPLIT, 2, 1, half_t><<<dim3(256, 1, 1), 512, 0, stream>>>(
        S, vt, part, nullptr, NSP / KSPLIT, NSP, NSP, CH, bNN, bNC, bNC);
    // out = combine(part)/rowsum @ wp^T + bp + x  (fused combine, EPI=4)
    gemm_nt<64, 64, 128, 4, 2, 1, float><<<dim3(BATCH * NSP / 64, CH / 64, 1), 256, 0, stream>>>(
        part, wpT, out, bp, nullptr, nullptr, x, rsum, BATCH * NSP, CH, CH,
        CH, CH, CH, 0, 0, 0, 1.f);
  } else {
    for (int bb = 0; bb < BATCH; ++bb) {
      gemm8p<3, 1, 1, 1, half_t><<<dim3(16, 16, 1), 512, 0, stream>>>(
          q + bb * bQKV, k + bb * bQKV, S, rsum + bb * NSP, CH,
          NQKV, NQKV, NSP, 0, 0, 0);
      gemm8p<0, KSPLIT, 0, 1, half_t><<<dim3(NSP / 256, CH / 256, KSPLIT), 512, 0, stream>>>(
          S, vt + bb * bNC, part + (long)bb * KSPLIT * bNC, nullptr,
          NSP / KSPLIT, NSP, NSP, CH, 0, 0, bNC);
    }
    pv_combine<<<2048, 256, 0, stream>>>(part, rsum, ao);
    gemm_nt<64, 64, 128, 2, 2, 1, float><<<dim3(BATCH * NSP / 64, CH / 64, 1), 256, 0, stream>>>(
        ao, wpT, out, bp, nullptr, nullptr, x, nullptr, BATCH * NSP, CH, CH,
        CH, CH, CH, 0, 0, 0, 1.f);
  }
}